// Round 1
// baseline (243.956 us; speedup 1.0000x reference)
//
#include <hip/hip_runtime.h>
#include <cstdint>
#include <cstddef>

#define NIMG 256
#define PADW 18
#define XB_IMG (PADW * PADW * 256)   // 82944 elements per image
#define W2_ROW 2304                  // 9*256

typedef __bf16 bf16x8 __attribute__((ext_vector_type(8)));
typedef float floatx4 __attribute__((ext_vector_type(4)));

__device__ __forceinline__ unsigned short f2bf(float f) {
    unsigned u = __float_as_uint(f);
    u = (u + 0x7FFFu + ((u >> 16) & 1u)) >> 16;   // RNE
    return (unsigned short)u;
}

__device__ __forceinline__ void gload_lds16(const void* g, void* l) {
    __builtin_amdgcn_global_load_lds(
        (const __attribute__((address_space(1))) void*)g,
        (__attribute__((address_space(3))) void*)l, 16, 0, 0);
}

// ---------------------------------------------------------------------------
// Kernel 1: x NCHW fp32 -> xb[n][py][px][c] bf16, spatially padded (18x18),
// halo zeroed. Channel-contiguous per pixel so GEMM A-tiles stage with
// global_load_lds dwordx4 and no boundary checks.
// grid (256 images, 4 c-groups of 64), block 256.
// ---------------------------------------------------------------------------
__global__ __launch_bounds__(256) void convert_kernel(
        const float* __restrict__ x, unsigned short* __restrict__ xb) {
    __shared__ __align__(16) unsigned short tile[256][66];  // pad 66: 2-way max
    const int n  = blockIdx.x;
    const int c0 = blockIdx.y * 64;
    const int t  = threadIdx.x;
    const float* xi = x + (size_t)n * 65536;
    unsigned short* xo = xb + (size_t)n * XB_IMG;

    // halo zero (68 border pixels * 256 ch), done once per image by c-group 0
    if (blockIdx.y == 0) {
        for (int idx = t; idx < 68 * 128; idx += 256) {
            int hp = idx >> 7;
            int c2 = (idx & 127) * 2;
            int py, px;
            if (hp < 18)      { py = 0;       px = hp;      }
            else if (hp < 36) { py = 17;      px = hp - 18; }
            else if (hp < 52) { py = hp - 35; px = 0;       }
            else              { py = hp - 51; px = 17;      }
            *(unsigned int*)&xo[(py * 18 + px) * 256 + c2] = 0u;
        }
    }

    // load 64 channels (coalesced along pixels), transpose via LDS
    #pragma unroll 4
    for (int i = 0; i < 64; ++i) {
        float v = xi[(c0 + i) * 256 + t];
        tile[t][i] = f2bf(v);
    }
    __syncthreads();

    // write out: per pixel, 64 contiguous bf16 channels
    #pragma unroll
    for (int it = 0; it < 32; ++it) {
        int idx = it * 256 + t;
        int p   = idx >> 5;
        int c2  = (idx & 31) * 2;
        unsigned int v = *(const unsigned int*)&tile[p][c2];
        int py = (p >> 4) + 1, px = (p & 15) + 1;
        *(unsigned int*)&xo[(py * 18 + px) * 256 + c0 + c2] = v;
    }
}

// ---------------------------------------------------------------------------
// Kernel 2: combined weight w2[kout][pos][c] bf16 (K-order = (kh*3+kw, c)).
//   w_comb[o,ic,pos] = a0*wt[o,ic,pos]
//                    + sum_b a_b * (1/b) * sum_j wt[ob+j, icb+(j+i)%b, pos],
//   ob=o-o%b, icb=ic-ic%b, i=(o%b-ic%b)%b.
// grid (16 o-blocks, 9 pos), block 256 (thread = ic).
// ---------------------------------------------------------------------------
__global__ __launch_bounds__(256) void wprep_kernel(
        const float* __restrict__ wt, const float* __restrict__ alphas,
        unsigned short* __restrict__ w2) {
    __shared__ float wlds[16][257];
    const int o16 = blockIdx.x * 16;
    const int pos = blockIdx.y;
    const int t   = threadIdx.x;

    #pragma unroll
    for (int j = 0; j < 16; ++j)
        wlds[j][t] = wt[((o16 + j) * 256 + t) * 9 + pos];

    float a[5];
    {
        float mx = alphas[0];
        #pragma unroll
        for (int i = 1; i < 5; ++i) mx = fmaxf(mx, alphas[i]);
        float s = 0.f;
        #pragma unroll
        for (int i = 0; i < 5; ++i) { a[i] = __expf(alphas[i] - mx); s += a[i]; }
        float inv = 1.f / s;
        #pragma unroll
        for (int i = 0; i < 5; ++i) a[i] *= inv;
    }
    __syncthreads();

    const int c = t;
    #pragma unroll
    for (int oo = 0; oo < 16; ++oo) {
        float acc = a[0] * wlds[oo][c];
        #pragma unroll
        for (int bi = 0; bi < 4; ++bi) {
            const int b  = 2 << bi;            // 2,4,8,16
            const int r  = oo & (b - 1);
            const int cc = c & (b - 1);
            const int i0 = (r - cc) & (b - 1);
            const int ob = oo - r;
            const int icb = c - cc;
            float s2 = 0.f;
            for (int j = 0; j < b; ++j)
                s2 += wlds[ob + j][icb + ((j + i0) & (b - 1))];
            acc += a[1 + bi] * s2 * (1.f / (float)b);
        }
        w2[(size_t)(o16 + oo) * W2_ROW + pos * 256 + c] = f2bf(acc);
    }
}

// ---------------------------------------------------------------------------
// Kernel 3: implicit-GEMM conv. D[kout][pixel] per 128x128 tile.
// K = 9 positions x 256 ch, BK=32. 4 waves, each 64x64 (4x4 MFMA 16x16x32).
// grid (512 pixel-tiles, 2 kout-tiles), block 256.
// ---------------------------------------------------------------------------
__global__ __launch_bounds__(256) void gemm_kernel(
        const unsigned short* __restrict__ xb,
        const unsigned short* __restrict__ w2,
        float* __restrict__ out) {
    __shared__ __align__(16) unsigned short xs[128 * 32];  // [pixel][c] 8 KB
    __shared__ __align__(16) unsigned short ws[128 * 32];  // [kout][c]  8 KB

    const int t    = threadIdx.x;
    const int lane = t & 63;
    const int wid  = t >> 6;
    const int pt    = blockIdx.x;      // pixel tile: 2 per image
    const int n_img = pt >> 1;
    const int half  = pt & 1;
    const int kbase = blockIdx.y * 128;

    // staging: wave0/1 -> xs halves, wave2/3 -> ws halves. 4 x 1KB calls/wave.
    const int sub  = wid & 1;
    const int rlo  = lane >> 2;          // row within 16-row chunk
    const int coff = (lane & 3) * 8;     // channel offset (8 bf16 = 16 B)

    int xg[4], wg[4];
    #pragma unroll
    for (int i = 0; i < 4; ++i) {
        int tp = sub * 64 + i * 16 + rlo;           // tile pixel 0..127
        int y  = half * 8 + (tp >> 4);
        int xq = tp & 15;
        xg[i] = n_img * XB_IMG + ((y + 1) * 18 + (xq + 1)) * 256 + coff;
        int kr = kbase + sub * 64 + i * 16 + rlo;
        wg[i] = kr * W2_ROW + coff;
    }
    const int lds_base = sub * 4 * 512;  // element offset of this wave's chunks

    const floatx4 z4 = {0.f, 0.f, 0.f, 0.f};
    floatx4 acc[4][4];
    #pragma unroll
    for (int i = 0; i < 4; ++i)
        #pragma unroll
        for (int j = 0; j < 4; ++j) acc[i][j] = z4;

    const int wrow = wid >> 1, wcol = wid & 1;
    const int a_off = (wrow * 64 + (lane & 15)) * 32 + (lane >> 4) * 8;
    const int b_off = (wcol * 64 + (lane & 15)) * 32 + (lane >> 4) * 8;

    for (int pos = 0; pos < 9; ++pos) {
        const int dp = ((pos / 3) - 1) * (18 * 256) + ((pos % 3) - 1) * 256;
        #pragma unroll
        for (int cs = 0; cs < 8; ++cs) {
            const int kt32 = pos * 256 + cs * 32;
            __syncthreads();
            if (wid < 2) {
                #pragma unroll
                for (int i = 0; i < 4; ++i)
                    gload_lds16(xb + xg[i] + dp + cs * 32, &xs[lds_base + i * 512]);
            } else {
                #pragma unroll
                for (int i = 0; i < 4; ++i)
                    gload_lds16(w2 + wg[i] + kt32, &ws[lds_base + i * 512]);
            }
            __syncthreads();

            bf16x8 af[4], bfr[4];
            #pragma unroll
            for (int mt = 0; mt < 4; ++mt)
                af[mt] = *(const bf16x8*)&ws[a_off + mt * 512];
            #pragma unroll
            for (int nt = 0; nt < 4; ++nt)
                bfr[nt] = *(const bf16x8*)&xs[b_off + nt * 512];
            #pragma unroll
            for (int mt = 0; mt < 4; ++mt)
                #pragma unroll
                for (int nt = 0; nt < 4; ++nt)
                    acc[mt][nt] = __builtin_amdgcn_mfma_f32_16x16x32_bf16(
                        af[mt], bfr[nt], acc[mt][nt], 0, 0, 0);
        }
    }

    // epilogue: C/D layout col=lane&15 (pixel, coalesced), row=(lane>>4)*4+r (kout)
    const int p0 = half * 128 + wcol * 64;
    const int k0 = kbase + wrow * 64;
    float* ob = out + (size_t)n_img * 65536;
    #pragma unroll
    for (int mt = 0; mt < 4; ++mt) {
        #pragma unroll
        for (int nt = 0; nt < 4; ++nt) {
            const int kout = k0 + mt * 16 + (lane >> 4) * 4;
            const int p    = p0 + nt * 16 + (lane & 15);
            #pragma unroll
            for (int r = 0; r < 4; ++r)
                ob[(kout + r) * 256 + p] = acc[mt][nt][r];
        }
    }
}

// ---------------------------------------------------------------------------
// Fallback (only if workspace too small for xb): naive conv using w2.
// ---------------------------------------------------------------------------
__global__ __launch_bounds__(256) void naive_conv(
        const float* __restrict__ x, const unsigned short* __restrict__ w2,
        float* __restrict__ out) {
    __shared__ float wr[2304];
    const int n = blockIdx.x >> 8, k = blockIdx.x & 255;
    const int t = threadIdx.x;
    for (int i = t; i < 2304; i += 256)
        wr[i] = __uint_as_float(((unsigned)w2[k * W2_ROW + i]) << 16);
    __syncthreads();
    const int y = t >> 4, xx = t & 15;
    const float* xi = x + (size_t)n * 65536;
    float acc = 0.f;
    for (int pos = 0; pos < 9; ++pos) {
        int dy = pos / 3 - 1, dx = pos % 3 - 1;
        int yy = y + dy, x2 = xx + dx;
        if (yy < 0 || yy > 15 || x2 < 0 || x2 > 15) continue;
        const float* xp = xi + yy * 16 + x2;
        const float* wp = wr + pos * 256;
        for (int c = 0; c < 256; ++c) acc += xp[c * 256] * wp[c];
    }
    out[(size_t)n * 65536 + k * 256 + t] = acc;
}

extern "C" void kernel_launch(void* const* d_in, const int* in_sizes, int n_in,
                              void* d_out, int out_size, void* d_ws, size_t ws_size,
                              hipStream_t stream) {
    const float* x      = (const float*)d_in[0];
    const float* wt     = (const float*)d_in[1];
    const float* alphas = (const float*)d_in[2];
    float* out = (float*)d_out;

    const size_t xb_elems = (size_t)NIMG * XB_IMG;          // 21,233,664
    const size_t w2_elems = (size_t)256 * W2_ROW;           //    589,824
    const size_t need = (xb_elems + w2_elems) * sizeof(unsigned short); // ~41.6 MB

    if (ws_size >= need) {
        unsigned short* xb = (unsigned short*)d_ws;
        unsigned short* w2 = xb + xb_elems;
        convert_kernel<<<dim3(256, 4), 256, 0, stream>>>(x, xb);
        wprep_kernel<<<dim3(16, 9), 256, 0, stream>>>(wt, alphas, w2);
        gemm_kernel<<<dim3(512, 2), 256, 0, stream>>>(xb, w2, out);
    } else if (ws_size >= w2_elems * sizeof(unsigned short)) {
        unsigned short* w2 = (unsigned short*)d_ws;
        wprep_kernel<<<dim3(16, 9), 256, 0, stream>>>(wt, alphas, w2);
        naive_conv<<<dim3(256 * 256), 256, 0, stream>>>(x, w2, out);
    }
    // else: workspace insufficient for any correct path (will fail visibly)
}

// Round 2
// 214.857 us; speedup vs baseline: 1.1354x; 1.1354x over previous
//
#include <hip/hip_runtime.h>
#include <cstdint>
#include <cstddef>

#define NIMG 256
#define PADW 18
#define XB_IMG (PADW * PADW * 256)   // 82944 elements per image
#define W2_ROW 2304                  // 9*256

typedef __bf16 bf16x8 __attribute__((ext_vector_type(8)));
typedef float floatx4 __attribute__((ext_vector_type(4)));

__device__ __forceinline__ unsigned short f2bf(float f) {
    unsigned u = __float_as_uint(f);
    u = (u + 0x7FFFu + ((u >> 16) & 1u)) >> 16;   // RNE
    return (unsigned short)u;
}

__device__ __forceinline__ void gload_lds16(const void* g, void* l) {
    __builtin_amdgcn_global_load_lds(
        (const __attribute__((address_space(1))) void*)g,
        (__attribute__((address_space(3))) void*)l, 16, 0, 0);
}

// ---------------------------------------------------------------------------
// Kernel 1: x NCHW fp32 -> xb[n][py][px][c] bf16, spatially padded (18x18),
// halo zeroed. (unchanged from R1 — not the bottleneck)
// ---------------------------------------------------------------------------
__global__ __launch_bounds__(256) void convert_kernel(
        const float* __restrict__ x, unsigned short* __restrict__ xb) {
    __shared__ __align__(16) unsigned short tile[256][66];
    const int n  = blockIdx.x;
    const int c0 = blockIdx.y * 64;
    const int t  = threadIdx.x;
    const float* xi = x + (size_t)n * 65536;
    unsigned short* xo = xb + (size_t)n * XB_IMG;

    if (blockIdx.y == 0) {
        for (int idx = t; idx < 68 * 128; idx += 256) {
            int hp = idx >> 7;
            int c2 = (idx & 127) * 2;
            int py, px;
            if (hp < 18)      { py = 0;       px = hp;      }
            else if (hp < 36) { py = 17;      px = hp - 18; }
            else if (hp < 52) { py = hp - 35; px = 0;       }
            else              { py = hp - 51; px = 17;      }
            *(unsigned int*)&xo[(py * 18 + px) * 256 + c2] = 0u;
        }
    }

    #pragma unroll 4
    for (int i = 0; i < 64; ++i) {
        float v = xi[(c0 + i) * 256 + t];
        tile[t][i] = f2bf(v);
    }
    __syncthreads();

    #pragma unroll
    for (int it = 0; it < 32; ++it) {
        int idx = it * 256 + t;
        int p   = idx >> 5;
        int c2  = (idx & 31) * 2;
        unsigned int v = *(const unsigned int*)&tile[p][c2];
        int py = (p >> 4) + 1, px = (p & 15) + 1;
        *(unsigned int*)&xo[(py * 18 + px) * 256 + c0 + c2] = v;
    }
}

// ---------------------------------------------------------------------------
// Kernel 2: combined circulant weight w2[kout][pos][c] bf16. (unchanged)
// ---------------------------------------------------------------------------
__global__ __launch_bounds__(256) void wprep_kernel(
        const float* __restrict__ wt, const float* __restrict__ alphas,
        unsigned short* __restrict__ w2) {
    __shared__ float wlds[16][257];
    const int o16 = blockIdx.x * 16;
    const int pos = blockIdx.y;
    const int t   = threadIdx.x;

    #pragma unroll
    for (int j = 0; j < 16; ++j)
        wlds[j][t] = wt[((o16 + j) * 256 + t) * 9 + pos];

    float a[5];
    {
        float mx = alphas[0];
        #pragma unroll
        for (int i = 1; i < 5; ++i) mx = fmaxf(mx, alphas[i]);
        float s = 0.f;
        #pragma unroll
        for (int i = 0; i < 5; ++i) { a[i] = __expf(alphas[i] - mx); s += a[i]; }
        float inv = 1.f / s;
        #pragma unroll
        for (int i = 0; i < 5; ++i) a[i] *= inv;
    }
    __syncthreads();

    const int c = t;
    #pragma unroll
    for (int oo = 0; oo < 16; ++oo) {
        float acc = a[0] * wlds[oo][c];
        #pragma unroll
        for (int bi = 0; bi < 4; ++bi) {
            const int b  = 2 << bi;            // 2,4,8,16
            const int r  = oo & (b - 1);
            const int cc = c & (b - 1);
            const int i0 = (r - cc) & (b - 1);
            const int ob = oo - r;
            const int icb = c - cc;
            float s2 = 0.f;
            for (int j = 0; j < b; ++j)
                s2 += wlds[ob + j][icb + ((j + i0) & (b - 1))];
            acc += a[1 + bi] * s2 * (1.f / (float)b);
        }
        w2[(size_t)(o16 + oo) * W2_ROW + pos * 256 + c] = f2bf(acc);
    }
}

// ---------------------------------------------------------------------------
// Kernel 3 v2: implicit-GEMM conv. 128 kout x 128 pixels per block, BK=64
// (36 K-steps instead of 72 -> half the barrier drains), XOR-swizzled LDS
// (conflict-free ds_read_b128), XCD-paired 1D grid (both k-tiles of a
// pixel-tile on one XCD for L2 x-reuse).
//
// LDS layout: buf[row][slot s], slot s (16B = 8ch) holds channel-group
// (s - row)&7 of the current 64-ch K-slice. Stagers bake the swizzle into
// the per-lane GLOBAL address (LDS dest is fixed base+lane*16); readers use
// s = (kg + row)&7. Bank histogram uniform -> 2-way (free).
// ---------------------------------------------------------------------------
__global__ __launch_bounds__(256) void gemm_kernel(
        const unsigned short* __restrict__ xb,
        const unsigned short* __restrict__ w2,
        float* __restrict__ out) {
    __shared__ __align__(16) unsigned short xs[128 * 64];  // [pixel][64ch] 16 KB
    __shared__ __align__(16) unsigned short ws[128 * 64];  // [kout ][64ch] 16 KB

    const int t    = threadIdx.x;
    const int lane = t & 63;
    const int wid  = t >> 6;

    // XCD-paired decode: b&7 = XCD slot; both ktiles of a ptile share it.
    const int b     = blockIdx.x;
    const int s_    = b >> 3;                   // 0..127
    const int ptile = (b & 7) * 64 + (s_ >> 1); // 0..511
    const int ktile = s_ & 1;
    const int n_img = ptile >> 1;
    const int half  = ptile & 1;
    const int kbase = ktile * 128;

    // ---- staging addresses: waves 0/1 -> xs, waves 2/3 -> ws; 8 rows/instr
    const int rlo  = lane >> 3;                        // row within 8-row chunk
    const int cswz = ((lane & 7) - rlo) & 7;           // swizzled ch-group
    const int coff = cswz * 8;                         // element offset

    int xg[8], wg[8];
    {
        const int sub = wid & 1;                       // which 64-row half
        #pragma unroll
        for (int i = 0; i < 8; ++i) {
            int r = sub * 64 + i * 8 + rlo;            // tile row 0..127
            int y  = half * 8 + (r >> 4);
            int xq = r & 15;
            xg[i] = n_img * XB_IMG + ((y + 1) * 18 + (xq + 1)) * 256 + coff;
            int kr = kbase + sub * 64 + i * 8 + rlo;
            wg[i] = kr * W2_ROW + coff;
        }
    }
    const int lds_base = (wid & 1) * 4096;             // element offset

    const floatx4 z4 = {0.f, 0.f, 0.f, 0.f};
    floatx4 acc[4][4];
    #pragma unroll
    for (int i = 0; i < 4; ++i)
        #pragma unroll
        for (int j = 0; j < 4; ++j) acc[i][j] = z4;

    // ---- reader offsets (swizzled)
    const int wrow = wid >> 1, wcol = wid & 1;
    const int arow = wrow * 64 + (lane & 15);
    const int brow = wcol * 64 + (lane & 15);
    const int sa0  = (arow + (lane >> 4)) & 7;   // slot for ks=0; ks=1 -> ^4
    const int sb0  = (brow + (lane >> 4)) & 7;

    for (int pos = 0; pos < 9; ++pos) {
        const int dp = ((pos / 3) - 1) * (18 * 256) + ((pos % 3) - 1) * 256;
        #pragma unroll
        for (int cs = 0; cs < 4; ++cs) {
            __syncthreads();
            if (wid < 2) {
                const int go = dp + cs * 64;
                #pragma unroll
                for (int i = 0; i < 8; ++i)
                    gload_lds16(xb + xg[i] + go, &xs[lds_base + i * 512]);
            } else {
                const int go = pos * 256 + cs * 64;
                #pragma unroll
                for (int i = 0; i < 8; ++i)
                    gload_lds16(w2 + wg[i] + go, &ws[lds_base + i * 512]);
            }
            __syncthreads();

            #pragma unroll
            for (int ks = 0; ks < 2; ++ks) {
                const int sa = (sa0 + ks * 4) & 7;
                const int sb = (sb0 + ks * 4) & 7;
                bf16x8 af[4], bfr[4];
                #pragma unroll
                for (int mt = 0; mt < 4; ++mt)
                    af[mt] = *(const bf16x8*)&ws[(arow + mt * 16) * 64 + sa * 8];
                #pragma unroll
                for (int nt = 0; nt < 4; ++nt)
                    bfr[nt] = *(const bf16x8*)&xs[(brow + nt * 16) * 64 + sb * 8];
                #pragma unroll
                for (int mt = 0; mt < 4; ++mt)
                    #pragma unroll
                    for (int nt = 0; nt < 4; ++nt)
                        acc[mt][nt] = __builtin_amdgcn_mfma_f32_16x16x32_bf16(
                            af[mt], bfr[nt], acc[mt][nt], 0, 0, 0);
            }
        }
    }

    // epilogue: C/D layout col=lane&15 (pixel, coalesced), row=(lane>>4)*4+r
    const int p0 = half * 128 + wcol * 64;
    const int k0 = kbase + wrow * 64;
    float* ob = out + (size_t)n_img * 65536;
    #pragma unroll
    for (int mt = 0; mt < 4; ++mt) {
        #pragma unroll
        for (int nt = 0; nt < 4; ++nt) {
            const int kout = k0 + mt * 16 + (lane >> 4) * 4;
            const int p    = p0 + nt * 16 + (lane & 15);
            #pragma unroll
            for (int r = 0; r < 4; ++r)
                ob[(kout + r) * 256 + p] = acc[mt][nt][r];
        }
    }
}

// ---------------------------------------------------------------------------
// Fallback (only if workspace too small for xb): naive conv using w2.
// ---------------------------------------------------------------------------
__global__ __launch_bounds__(256) void naive_conv(
        const float* __restrict__ x, const unsigned short* __restrict__ w2,
        float* __restrict__ out) {
    __shared__ float wr[2304];
    const int n = blockIdx.x >> 8, k = blockIdx.x & 255;
    const int t = threadIdx.x;
    for (int i = t; i < 2304; i += 256)
        wr[i] = __uint_as_float(((unsigned)w2[k * W2_ROW + i]) << 16);
    __syncthreads();
    const int y = t >> 4, xx = t & 15;
    const float* xi = x + (size_t)n * 65536;
    float acc = 0.f;
    for (int pos = 0; pos < 9; ++pos) {
        int dy = pos / 3 - 1, dx = pos % 3 - 1;
        int yy = y + dy, x2 = xx + dx;
        if (yy < 0 || yy > 15 || x2 < 0 || x2 > 15) continue;
        const float* xp = xi + yy * 16 + x2;
        const float* wp = wr + pos * 256;
        for (int c = 0; c < 256; ++c) acc += xp[c * 256] * wp[c];
    }
    out[(size_t)n * 65536 + k * 256 + t] = acc;
}

extern "C" void kernel_launch(void* const* d_in, const int* in_sizes, int n_in,
                              void* d_out, int out_size, void* d_ws, size_t ws_size,
                              hipStream_t stream) {
    const float* x      = (const float*)d_in[0];
    const float* wt     = (const float*)d_in[1];
    const float* alphas = (const float*)d_in[2];
    float* out = (float*)d_out;

    const size_t xb_elems = (size_t)NIMG * XB_IMG;          // 21,233,664
    const size_t w2_elems = (size_t)256 * W2_ROW;           //    589,824
    const size_t need = (xb_elems + w2_elems) * sizeof(unsigned short); // ~41.6 MB

    if (ws_size >= need) {
        unsigned short* xb = (unsigned short*)d_ws;
        unsigned short* w2 = xb + xb_elems;
        convert_kernel<<<dim3(256, 4), 256, 0, stream>>>(x, xb);
        wprep_kernel<<<dim3(16, 9), 256, 0, stream>>>(wt, alphas, w2);
        gemm_kernel<<<dim3(1024), 256, 0, stream>>>(xb, w2, out);
    } else if (ws_size >= w2_elems * sizeof(unsigned short)) {
        unsigned short* w2 = (unsigned short*)d_ws;
        wprep_kernel<<<dim3(16, 9), 256, 0, stream>>>(wt, alphas, w2);
        naive_conv<<<dim3(256 * 256), 256, 0, stream>>>(x, w2, out);
    }
}